// Round 13
// baseline (1227.688 us; speedup 1.0000x reference)
//
#include <hip/hip_runtime.h>
#include <cstdint>

#define KU 256
#define NBASK 64
#define MBS 20
#define BITEMS 1280
#define HD 256
#define G3 768
#define TT 64

typedef short v8s __attribute__((ext_vector_type(8)));
typedef float v4f __attribute__((ext_vector_type(4)));
typedef unsigned short v4us __attribute__((ext_vector_type(4)));
typedef unsigned int v4u __attribute__((ext_vector_type(4)));

__device__ __forceinline__ unsigned short f2b(float f){
  uint32_t u = __float_as_uint(f);
  u += 0x7FFFu + ((u >> 16) & 1u);
  return (unsigned short)(u >> 16);
}
__device__ __forceinline__ float b2f(unsigned short s){
  return __uint_as_float(((uint32_t)s) << 16);
}
__device__ __forceinline__ unsigned int packf(float x){
  unsigned short hi = f2b(x);
  unsigned short lo = f2b(x - b2f(hi));
  return ((unsigned int)hi << 16) | lo;
}
__device__ __forceinline__ float unpackf(unsigned int v){
  return b2f((unsigned short)(v >> 16)) + b2f((unsigned short)(v & 0xffffu));
}
__device__ __forceinline__ void waitflag(int* f, int v){
  while (__hip_atomic_load(f, __ATOMIC_ACQUIRE, __HIP_MEMORY_SCOPE_AGENT) < v)
    __builtin_amdgcn_s_sleep(2);
}

// ---------------- weight conversion: fp32 -> bf16 hi + residual lo ---------
__global__ __launch_bounds__(1024) void k_convert(
    const float* __restrict__ wih, const float* __restrict__ whh,
    unsigned short* __restrict__ wih1hi, unsigned short* __restrict__ wih1lo,
    unsigned short* __restrict__ wih2hi, unsigned short* __restrict__ wih2lo,
    unsigned short* __restrict__ whh1hi, unsigned short* __restrict__ whh1lo,
    unsigned short* __restrict__ whh2hi, unsigned short* __restrict__ whh2lo)
{
  int idx = blockIdx.x * 1024 + threadIdx.x;     // 0..196607
  int which = blockIdx.y;
  float v;
  if (which == 0)      v = wih[idx];
  else if (which == 1) v = wih[196608 + idx];
  else if (which == 2) v = whh[idx];
  else                 v = whh[196608 + idx];
  unsigned short hi = f2b(v);
  unsigned short lo = f2b(v - b2f(hi));
  if (which == 0)      { wih1hi[idx] = hi; wih1lo[idx] = lo; }
  else if (which == 1) { wih2hi[idx] = hi; wih2lo[idx] = lo; }
  else if (which == 2) { whh1hi[idx] = hi; whh1lo[idx] = lo; }
  else                 { whh2hi[idx] = hi; whh2lo[idx] = lo; }
}

// ---------------- flag init ------------------------------------------------
__global__ void k_zero(int* flags){
  if (threadIdx.x < 128) flags[threadIdx.x] = 0;
}

// ---------------- per-user basket ordering (stable: valid first) -----------
__global__ __launch_bounds__(64) void k_order(
    const float* __restrict__ prob, const int* __restrict__ seq,
    int* __restrict__ order, int* __restrict__ lengths)
{
  int k = blockIdx.x, j = threadIdx.x;           // j = basket
  int base = k * BITEMS + j * MBS;
  float mx = 0.f;
  #pragma unroll
  for (int m = 0; m < MBS; m++) {
    int it = seq[base + m];
    float p = (it >= 0) ? prob[base + m] : 0.f;
    mx = fmaxf(mx, p);
  }
  bool valid = mx > 0.f;
  unsigned long long bal = __ballot(valid);
  int len = __popcll(bal);
  unsigned long long below = bal & ((1ull << j) - 1ull);
  int pos = valid ? __popcll(below) : (len + (j - __popcll(below)));
  order[k * NBASK + j] = pos;
  if (j == 0) lengths[k] = (len > 0) ? len : 1;
}

// ---------------- basket pooling -> ordered x (packed bf16 hi|lo u32) ------
__global__ __launch_bounds__(256) void k_basket(
    const float* __restrict__ prob, const int* __restrict__ seq,
    const float* __restrict__ table, const int* __restrict__ order,
    unsigned int* __restrict__ xb)
{
  int j = blockIdx.x, k = blockIdx.y;
  int h = threadIdx.x;
  int base = k * BITEMS + j * MBS;
  float acc = 0.f, sp = 0.f;
  #pragma unroll
  for (int m = 0; m < MBS; m++) {
    int it = seq[base + m];
    if (it >= 0) {
      float p = prob[base + m];
      sp += p;
      acc += p * table[(size_t)(it + 1) * HD + h];
    }
  }
  float val = acc / (sp + 1e-10f);
  int dest = order[k * NBASK + j];
  xb[((size_t)k * NBASK + dest) * HD + h] = packf(val);
}

// ---------------- full-step weight prefetch (24 loads upfront) -------------
__device__ __forceinline__ void wload_all(
    const unsigned short* __restrict__ w0, const unsigned short* __restrict__ w1,
    const unsigned short* __restrict__ w2, int half4,
    v8s (&cw0)[8], v8s (&cw1)[8], v8s (&cw2)[8])
{
  #pragma unroll
  for (int kk = 0; kk < 8; kk++) {
    int p = (half4 + kk) & 7;
    cw0[kk] = *(const v8s*)(w0 + p * 32);
    cw1[kk] = *(const v8s*)(w1 + p * 32);
    cw2[kk] = *(const v8s*)(w2 + p * 32);
  }
}
template<int K0, int KN>
__device__ __forceinline__ void mfma_run(
    const unsigned short (*h_hi)[256], const unsigned short (*h_lo)[256],
    const unsigned short* __restrict__ nlo_s, int r, int g, int jloc, int half4,
    const v8s (&cw0)[8], const v8s (&cw1)[8], const v8s (&cw2)[8],
    v4f& a0, v4f& a1, v4f& a2)
{
  #pragma unroll
  for (int kk = K0; kk < KN; kk++) {
    int p = (half4 + kk) & 7;
    int slotA = ((p * 4 + g) ^ (r & 7)) * 8;
    v8s ahi = *(const v8s*)&h_hi[r][slotA];
    v8s alo = *(const v8s*)&h_lo[r][slotA];
    v8s nl  = *(const v8s*)&nlo_s[jloc * 256 + slotA];
    a0 = __builtin_amdgcn_mfma_f32_16x16x32_bf16(ahi, cw0[kk], a0, 0, 0, 0);
    a0 = __builtin_amdgcn_mfma_f32_16x16x32_bf16(alo, cw0[kk], a0, 0, 0, 0);
    a1 = __builtin_amdgcn_mfma_f32_16x16x32_bf16(ahi, cw1[kk], a1, 0, 0, 0);
    a1 = __builtin_amdgcn_mfma_f32_16x16x32_bf16(alo, cw1[kk], a1, 0, 0, 0);
    a2 = __builtin_amdgcn_mfma_f32_16x16x32_bf16(ahi, cw2[kk], a2, 0, 0, 0);
    a2 = __builtin_amdgcn_mfma_f32_16x16x32_bf16(alo, cw2[kk], a2, 0, 0, 0);
    a2 = __builtin_amdgcn_mfma_f32_16x16x32_bf16(ahi, nl, a2, 0, 0, 0);
  }
}

// ---------------- 4-stage pipelined GRU (128 blocks x 512) -----------------
// role = bx>>5: 0 = G1 (gi1 = xb @ wih1^T + bih1; free-runs, no upstream),
// 1 = A (layer-1 recurrence), 2 = G2 (gi2 = h1 @ wih2^T), 3 = B (layer-2).
// sub = bx&31 -> half = sub>>4, user group b = sub&15. All 4 roles of a chain
// share an XCD (bx%8 invariant). Slot lifecycle in pk[u][t]: packed xb
// (k_basket) -> read by G1(t) -> overwritten by A(t) with packed h1(t) ->
// read by G2(t) and A-sibling: each transition flag-ordered. gi[u][t]: packed
// gi1 (G1) -> read by A(t) -> overwritten by G2(t) with gi2 -> read by B(t).
__global__ __launch_bounds__(512) void k_pipe(
    const unsigned short* __restrict__ wih1hi, const unsigned short* __restrict__ wih1lo,
    const unsigned short* __restrict__ whh1hi, const unsigned short* __restrict__ whh1lo,
    const unsigned short* __restrict__ wih2hi, const unsigned short* __restrict__ wih2lo,
    const unsigned short* __restrict__ whh2hi, const unsigned short* __restrict__ whh2lo,
    float* __restrict__ gi, unsigned int* __restrict__ pk, unsigned int* __restrict__ h2x,
    const float* __restrict__ bih1, const float* __restrict__ bhh1,
    const float* __restrict__ bih2, const float* __restrict__ bhh2,
    const int* __restrict__ lengths, float* __restrict__ out, int* flags)
{
  __shared__ unsigned short h_hi[16][256], h_lo[16][256];  // 16 KB
  __shared__ unsigned short nlo_s[32768];                  // 64 KB
  int tid = threadIdx.x;
  int l = tid & 63, r = l & 15, g = l >> 4;
  int swv = __builtin_amdgcn_readfirstlane(tid >> 6);
  int bx = blockIdx.x;
  int role = bx >> 5, sub = bx & 31, half = sub >> 4, b = sub & 15;
  int half4 = half * 4;
  int ub = b * 16;
  int jloc = swv * 16 + r, j = half * 128 + jloc;
  int* aflag = flags, *gflag = flags + 32, *bflag = flags + 64, *g1flag = flags + 96;
  int myf = sub, sibf = sub ^ 16;

  const unsigned short* whi_g = (role == 0) ? wih1hi : (role == 1) ? whh1hi
                              : (role == 2) ? wih2hi : whh2hi;
  const unsigned short* wlo_g = (role == 0) ? wih1lo : (role == 1) ? whh1lo
                              : (role == 2) ? wih2lo : whh2lo;
  const float* bb_ = (role == 0) ? bih1 : (role == 1) ? bhh1
                   : (role == 2) ? bih2 : bhh2;

  for (int idx = tid; idx < 4096; idx += 512) {
    ((unsigned short*)h_hi)[idx] = 0;
    ((unsigned short*)h_lo)[idx] = 0;
  }
  // stage this block's n-gate lo rows (its j-half), MFMA-read swizzled
  const unsigned short* wlo_n = wlo_g + 2 * 65536 + half * 128 * 256;
  for (int idx = tid; idx < 32768; idx += 512) {
    int row = idx >> 8, col = idx & 255;
    int slot = (col >> 3) ^ (row & 7);
    nlo_s[row * 256 + slot * 8 + (col & 7)] = wlo_n[idx];
  }
  const unsigned short* w0 = whi_g + (size_t)j * 256 + g * 8;
  const unsigned short* w1 = w0 + 65536;
  const unsigned short* w2 = w0 + 131072;
  float b_r = bb_[j], b_z = bb_[256 + j], b_n = bb_[512 + j];
  int sibbase = (1 - half) * 128;
  int xu = tid >> 5;                           // exchange helper coords
  __syncthreads();

  if (role == 1) {
    // ===== stage A: layer-1 recurrence (j-half) =====
    float hold[4] = {0.f, 0.f, 0.f, 0.f};
    const unsigned int* gq[4];
    unsigned int* hq[4];
    #pragma unroll
    for (int i = 0; i < 4; i++) {
      gq[i] = (const unsigned int*)gi + (size_t)(ub + g * 4 + i) * TT * G3 + j;
      hq[i] = pk + (size_t)(ub + g * 4 + i) * TT * HD + j;
    }
    for (int t = 0; t < TT; t++) {
      v8s cw0[8], cw1[8], cw2[8];
      wload_all(w0, w1, w2, half4, cw0, cw1, cw2);     // 24 weight loads first
      waitflag(&g1flag[b], t + 1);                     // gi1(t) ready (both halves)
      waitflag(&g1flag[16 + b], t + 1);
      unsigned int vr[4], vz[4], vn[4];
      #pragma unroll
      for (int i = 0; i < 4; i++) {                    // packed gi1 loads after weights
        vr[i] = gq[i][0]; vz[i] = gq[i][256]; vn[i] = gq[i][512];
        gq[i] += G3;
      }
      v4f a0 = {0.f,0.f,0.f,0.f}, a1 = {0.f,0.f,0.f,0.f}, a2 = {0.f,0.f,0.f,0.f};
      mfma_run<0,4>(h_hi, h_lo, nlo_s, r, g, jloc, half4, cw0, cw1, cw2, a0, a1, a2);
      if (t > 0 && tid == 0) waitflag(&aflag[sibf], t);
      __syncthreads();                                 // B1
      if (t > 0) {
        int sj = sibbase + (tid & 31) * 4;
        v4u pkv = *(const v4u*)&pk[((size_t)(ub + xu) * TT + (t - 1)) * HD + sj];
        int pos = (((sj >> 3) ^ (xu & 7)) << 3) + (sj & 7);
        v4us hv, lv;
        #pragma unroll
        for (int i = 0; i < 4; i++) { hv[i] = (unsigned short)(pkv[i] >> 16); lv[i] = (unsigned short)(pkv[i] & 0xffffu); }
        *(v4us*)&h_hi[xu][pos] = hv;
        *(v4us*)&h_lo[xu][pos] = lv;
      }
      __syncthreads();                                 // B2
      mfma_run<4,8>(h_hi, h_lo, nlo_s, r, g, jloc, half4, cw0, cw1, cw2, a0, a1, a2);
      #pragma unroll
      for (int i = 0; i < 4; i++) {
        float hr = a0[i] + b_r, hz = a1[i] + b_z, hn = a2[i] + b_n;
        float rr = 1.f / (1.f + __expf(-(unpackf(vr[i]) + hr)));
        float zz = 1.f / (1.f + __expf(-(unpackf(vz[i]) + hz)));
        float e  = __expf(2.f * (unpackf(vn[i]) + rr * hn));
        float nn = 1.f - 2.f / (e + 1.f);
        float hnew = (1.f - zz) * nn + zz * hold[i];
        hold[i] = hnew;
        unsigned short h_  = f2b(hnew);
        unsigned short lo_ = f2b(hnew - b2f(h_));
        int u = g * 4 + i;
        int pos = (((j >> 3) ^ (u & 7)) << 3) + (j & 7);
        h_hi[u][pos] = h_;
        h_lo[u][pos] = lo_;
        hq[i][0] = ((unsigned int)h_ << 16) | lo_;     // h1(t) replaces xb(t) slot
        hq[i] += HD;
      }
      __syncthreads();                                 // B3
      if (tid == 0) {
        __threadfence();
        __hip_atomic_store(&aflag[myf], t + 1, __ATOMIC_RELEASE, __HIP_MEMORY_SCOPE_AGENT);
      }
    }
  } else if (role == 3) {
    // ===== stage B: layer-2 recurrence (j-half) =====
    float hold[4] = {0.f, 0.f, 0.f, 0.f};
    const unsigned int* gq[4];
    int lenr[4];
    #pragma unroll
    for (int i = 0; i < 4; i++) {
      gq[i] = (const unsigned int*)gi + (size_t)(ub + g * 4 + i) * TT * G3 + j;
      lenr[i] = lengths[ub + g * 4 + i];
    }
    for (int t = 0; t < TT; t++) {
      v8s cw0[8], cw1[8], cw2[8];
      wload_all(w0, w1, w2, half4, cw0, cw1, cw2);
      v4f a0 = {0.f,0.f,0.f,0.f}, a1 = {0.f,0.f,0.f,0.f}, a2 = {0.f,0.f,0.f,0.f};
      mfma_run<0,4>(h_hi, h_lo, nlo_s, r, g, jloc, half4, cw0, cw1, cw2, a0, a1, a2);
      if (tid == 0) {
        waitflag(&gflag[myf], t + 1);
        if (t > 0) waitflag(&bflag[sibf], t);
      }
      __syncthreads();                                 // B1
      if (t > 0) {
        int sj = sibbase + (tid & 31) * 4;
        v4u pkv = *(const v4u*)&h2x[(size_t)(ub + xu) * HD + sj];
        int pos = (((sj >> 3) ^ (xu & 7)) << 3) + (sj & 7);
        v4us hv, lv;
        #pragma unroll
        for (int i = 0; i < 4; i++) { hv[i] = (unsigned short)(pkv[i] >> 16); lv[i] = (unsigned short)(pkv[i] & 0xffffu); }
        *(v4us*)&h_hi[xu][pos] = hv;
        *(v4us*)&h_lo[xu][pos] = lv;
      }
      unsigned int vr[4], vz[4], vn[4];
      #pragma unroll
      for (int i = 0; i < 4; i++) {
        vr[i] = gq[i][0]; vz[i] = gq[i][256]; vn[i] = gq[i][512];
        gq[i] += G3;
      }
      __syncthreads();                                 // B2
      mfma_run<4,8>(h_hi, h_lo, nlo_s, r, g, jloc, half4, cw0, cw1, cw2, a0, a1, a2);
      #pragma unroll
      for (int i = 0; i < 4; i++) {
        float hr = a0[i] + b_r, hz = a1[i] + b_z, hn = a2[i] + b_n;
        float rr = 1.f / (1.f + __expf(-(unpackf(vr[i]) + hr)));
        float zz = 1.f / (1.f + __expf(-(unpackf(vz[i]) + hz)));
        float e  = __expf(2.f * (unpackf(vn[i]) + rr * hn));
        float nn = 1.f - 2.f / (e + 1.f);
        float hnew = (1.f - zz) * nn + zz * hold[i];
        hold[i] = hnew;
        unsigned short h_  = f2b(hnew);
        unsigned short lo_ = f2b(hnew - b2f(h_));
        int u = g * 4 + i;
        int pos = (((j >> 3) ^ (u & 7)) << 3) + (j & 7);
        h_hi[u][pos] = h_;
        h_lo[u][pos] = lo_;
        h2x[(size_t)(ub + u) * HD + j] = ((unsigned int)h_ << 16) | lo_;
        if (t == lenr[i] - 1)
          out[(size_t)(ub + u) * HD + j] = hnew;
      }
      __syncthreads();                                 // B3
      if (tid == 0) {
        __threadfence();
        __hip_atomic_store(&bflag[myf], t + 1, __ATOMIC_RELEASE, __HIP_MEMORY_SCOPE_AGENT);
      }
    }
  } else {
    // ===== stage G1 (role 0) / G2 (role 2): gi(t) = X(t) @ W^T + bias ======
    // G1: X = xb (pre-staged by k_basket, no wait). G2: X = h1 (wait aflags).
    unsigned int* gi_u = (unsigned int*)gi;
    int* postf = (role == 0) ? &g1flag[myf] : &gflag[myf];
    for (int t = 0; t < TT; t++) {
      v8s cw0[8], cw1[8], cw2[8];
      wload_all(w0, w1, w2, half4, cw0, cw1, cw2);     // hidden under flag wait
      if (role == 2 && tid == 0) { waitflag(&aflag[b], t + 1); waitflag(&aflag[16 + b], t + 1); }
      __syncthreads();                                 // B1
      {
        int c0 = (tid & 31) * 8;
        const unsigned int* src = &pk[((size_t)(ub + xu) * TT + t) * HD + c0];
        #pragma unroll
        for (int hf = 0; hf < 2; hf++) {
          v4u pkv = *(const v4u*)(src + hf * 4);
          int sj = c0 + hf * 4;
          int pos = (((sj >> 3) ^ (xu & 7)) << 3) + (sj & 7);
          v4us hv, lv;
          #pragma unroll
          for (int i = 0; i < 4; i++) { hv[i] = (unsigned short)(pkv[i] >> 16); lv[i] = (unsigned short)(pkv[i] & 0xffffu); }
          *(v4us*)&h_hi[xu][pos] = hv;
          *(v4us*)&h_lo[xu][pos] = lv;
        }
      }
      __syncthreads();                                 // B2
      v4f a0 = {b_r, b_r, b_r, b_r}, a1 = {b_z, b_z, b_z, b_z}, a2 = {b_n, b_n, b_n, b_n};
      mfma_run<0,8>(h_hi, h_lo, nlo_s, r, g, jloc, half4, cw0, cw1, cw2, a0, a1, a2);
      #pragma unroll
      for (int i = 0; i < 4; i++) {
        size_t base = ((size_t)(ub + g * 4 + i) * TT + t) * G3;
        gi_u[base + j]       = packf(a0[i]);
        gi_u[base + 256 + j] = packf(a1[i]);
        gi_u[base + 512 + j] = packf(a2[i]);
      }
      __syncthreads();                                 // B3
      if (tid == 0) {
        __threadfence();
        __hip_atomic_store(postf, t + 1, __ATOMIC_RELEASE, __HIP_MEMORY_SCOPE_AGENT);
      }
    }
  }
}

extern "C" void kernel_launch(void* const* d_in, const int* in_sizes, int n_in,
                              void* d_out, int out_size, void* d_ws, size_t ws_size,
                              hipStream_t stream) {
  const float* prob  = (const float*)d_in[0];
  const int*   seq   = (const int*)d_in[1];
  // d_in[2] = uid (unused by the reference output)
  const float* table = (const float*)d_in[3];
  const float* wih   = (const float*)d_in[4];
  const float* whh   = (const float*)d_in[5];
  const float* bih   = (const float*)d_in[6];
  const float* bhh   = (const float*)d_in[7];
  float* out = (float*)d_out;

  char* ws = (char*)d_ws;
  float* gi          = (float*)ws;                     // 48 MiB packed u32: gi1 -> gi2
  unsigned int* pk   = (unsigned int*)(ws + 50331648); // 16 MiB: packed xb -> packed h1
  char* wsw = ws + 67108864;
  const size_t WSZ = 393216;                           // 768*256*2 B
  unsigned short* wih1hi = (unsigned short*)(wsw + 0 * WSZ);
  unsigned short* wih1lo = (unsigned short*)(wsw + 1 * WSZ);
  unsigned short* wih2hi = (unsigned short*)(wsw + 2 * WSZ);
  unsigned short* wih2lo = (unsigned short*)(wsw + 3 * WSZ);
  unsigned short* whh1hi = (unsigned short*)(wsw + 4 * WSZ);
  unsigned short* whh1lo = (unsigned short*)(wsw + 5 * WSZ);
  unsigned short* whh2hi = (unsigned short*)(wsw + 6 * WSZ);
  unsigned short* whh2lo = (unsigned short*)(wsw + 7 * WSZ);
  int* order   = (int*)(wsw + 8 * WSZ);                // 64 KB
  int* lengths = order + KU * NBASK;
  int* flags   = lengths + KU;
  unsigned int* h2x = (unsigned int*)(wsw + 8 * WSZ + 131072);  // 256 KB fresh

  k_zero<<<1, 128, 0, stream>>>(flags);
  k_convert<<<dim3(192, 4), 1024, 0, stream>>>(wih, whh,
      wih1hi, wih1lo, wih2hi, wih2lo, whh1hi, whh1lo, whh2hi, whh2lo);
  k_order<<<dim3(KU), 64, 0, stream>>>(prob, seq, order, lengths);
  k_basket<<<dim3(NBASK, KU), 256, 0, stream>>>(prob, seq, table, order, pk);
  // 4-stage pipeline: G1 (gi1) -> A (recur1) -> G2 (gi2) -> B (recur2)
  k_pipe<<<dim3(128), 512, 0, stream>>>(
      wih1hi, wih1lo, whh1hi, whh1lo, wih2hi, wih2lo, whh2hi, whh2lo,
      gi, pk, h2x, bih, bhh, bih + G3, bhh + G3, lengths, out, flags);
}

// Round 14
// 739.368 us; speedup vs baseline: 1.6605x; 1.6605x over previous
//
#include <hip/hip_runtime.h>
#include <cstdint>

#define KU 256
#define NBASK 64
#define MBS 20
#define BITEMS 1280
#define HD 256
#define G3 768
#define TT 64

typedef short v8s __attribute__((ext_vector_type(8)));
typedef float v4f __attribute__((ext_vector_type(4)));
typedef unsigned short v4us __attribute__((ext_vector_type(4)));
typedef unsigned int v4u __attribute__((ext_vector_type(4)));

__device__ __forceinline__ unsigned short f2b(float f){
  uint32_t u = __float_as_uint(f);
  u += 0x7FFFu + ((u >> 16) & 1u);
  return (unsigned short)(u >> 16);
}
__device__ __forceinline__ float b2f(unsigned short s){
  return __uint_as_float(((uint32_t)s) << 16);
}
__device__ __forceinline__ unsigned int packf(float x){
  unsigned short hi = f2b(x);
  unsigned short lo = f2b(x - b2f(hi));
  return ((unsigned int)hi << 16) | lo;
}
__device__ __forceinline__ float unpackf(unsigned int v){
  return b2f((unsigned short)(v >> 16)) + b2f((unsigned short)(v & 0xffffu));
}
__device__ __forceinline__ void waitflag(int* f, int v){
  while (__hip_atomic_load(f, __ATOMIC_ACQUIRE, __HIP_MEMORY_SCOPE_AGENT) < v)
    __builtin_amdgcn_s_sleep(2);
}

// ---------------- weight conversion (+ flag zeroing folded in) -------------
__global__ __launch_bounds__(1024) void k_convert(
    const float* __restrict__ wih, const float* __restrict__ whh,
    unsigned short* __restrict__ wih1hi, unsigned short* __restrict__ wih1lo,
    unsigned short* __restrict__ wih2hi, unsigned short* __restrict__ wih2lo,
    unsigned short* __restrict__ whh1hi, unsigned short* __restrict__ whh1lo,
    unsigned short* __restrict__ whh2hi, unsigned short* __restrict__ whh2lo,
    int* __restrict__ flags)
{
  int idx = blockIdx.x * 1024 + threadIdx.x;     // 0..196607
  int which = blockIdx.y;
  if (which == 0 && blockIdx.x == 0 && threadIdx.x < 128)
    flags[threadIdx.x] = 0;
  float v;
  if (which == 0)      v = wih[idx];
  else if (which == 1) v = wih[196608 + idx];
  else if (which == 2) v = whh[idx];
  else                 v = whh[196608 + idx];
  unsigned short hi = f2b(v);
  unsigned short lo = f2b(v - b2f(hi));
  if (which == 0)      { wih1hi[idx] = hi; wih1lo[idx] = lo; }
  else if (which == 1) { wih2hi[idx] = hi; wih2lo[idx] = lo; }
  else if (which == 2) { whh1hi[idx] = hi; whh1lo[idx] = lo; }
  else                 { whh2hi[idx] = hi; whh2lo[idx] = lo; }
}

// ---------------- per-user basket ordering (stable: valid first) -----------
__global__ __launch_bounds__(64) void k_order(
    const float* __restrict__ prob, const int* __restrict__ seq,
    int* __restrict__ order, int* __restrict__ lengths)
{
  int k = blockIdx.x, j = threadIdx.x;           // j = basket
  int base = k * BITEMS + j * MBS;
  float mx = 0.f;
  #pragma unroll
  for (int m = 0; m < MBS; m++) {
    int it = seq[base + m];
    float p = (it >= 0) ? prob[base + m] : 0.f;
    mx = fmaxf(mx, p);
  }
  bool valid = mx > 0.f;
  unsigned long long bal = __ballot(valid);
  int len = __popcll(bal);
  unsigned long long below = bal & ((1ull << j) - 1ull);
  int pos = valid ? __popcll(below) : (len + (j - __popcll(below)));
  order[k * NBASK + j] = pos;
  if (j == 0) lengths[k] = (len > 0) ? len : 1;
}

// ---------------- basket pooling -> ordered x (packed bf16 hi|lo u32) ------
__global__ __launch_bounds__(256) void k_basket(
    const float* __restrict__ prob, const int* __restrict__ seq,
    const float* __restrict__ table, const int* __restrict__ order,
    unsigned int* __restrict__ xb)
{
  int j = blockIdx.x, k = blockIdx.y;
  int h = threadIdx.x;
  int base = k * BITEMS + j * MBS;
  float acc = 0.f, sp = 0.f;
  #pragma unroll
  for (int m = 0; m < MBS; m++) {
    int it = seq[base + m];
    if (it >= 0) {
      float p = prob[base + m];
      sp += p;
      acc += p * table[(size_t)(it + 1) * HD + h];
    }
  }
  float val = acc / (sp + 1e-10f);
  int dest = order[k * NBASK + j];
  xb[((size_t)k * NBASK + dest) * HD + h] = packf(val);
}

// ---------------- full-step weight prefetch (24 loads upfront) -------------
__device__ __forceinline__ void wload_all(
    const unsigned short* __restrict__ w0, const unsigned short* __restrict__ w1,
    const unsigned short* __restrict__ w2, int half4,
    v8s (&cw0)[8], v8s (&cw1)[8], v8s (&cw2)[8])
{
  #pragma unroll
  for (int kk = 0; kk < 8; kk++) {
    int p = (half4 + kk) & 7;
    cw0[kk] = *(const v8s*)(w0 + p * 32);
    cw1[kk] = *(const v8s*)(w1 + p * 32);
    cw2[kk] = *(const v8s*)(w2 + p * 32);
  }
}
template<int K0, int KN>
__device__ __forceinline__ void mfma_run(
    const unsigned short (*h_hi)[256], const unsigned short (*h_lo)[256],
    const unsigned short* __restrict__ nlo_s, int r, int g, int jloc, int half4,
    const v8s (&cw0)[8], const v8s (&cw1)[8], const v8s (&cw2)[8],
    v4f& a0, v4f& a1, v4f& a2)
{
  #pragma unroll
  for (int kk = K0; kk < KN; kk++) {
    int p = (half4 + kk) & 7;
    int slotA = ((p * 4 + g) ^ (r & 7)) * 8;
    v8s ahi = *(const v8s*)&h_hi[r][slotA];
    v8s alo = *(const v8s*)&h_lo[r][slotA];
    v8s nl  = *(const v8s*)&nlo_s[jloc * 256 + slotA];
    a0 = __builtin_amdgcn_mfma_f32_16x16x32_bf16(ahi, cw0[kk], a0, 0, 0, 0);
    a0 = __builtin_amdgcn_mfma_f32_16x16x32_bf16(alo, cw0[kk], a0, 0, 0, 0);
    a1 = __builtin_amdgcn_mfma_f32_16x16x32_bf16(ahi, cw1[kk], a1, 0, 0, 0);
    a1 = __builtin_amdgcn_mfma_f32_16x16x32_bf16(alo, cw1[kk], a1, 0, 0, 0);
    a2 = __builtin_amdgcn_mfma_f32_16x16x32_bf16(ahi, cw2[kk], a2, 0, 0, 0);
    a2 = __builtin_amdgcn_mfma_f32_16x16x32_bf16(alo, cw2[kk], a2, 0, 0, 0);
    a2 = __builtin_amdgcn_mfma_f32_16x16x32_bf16(ahi, nl, a2, 0, 0, 0);
  }
}

// ---------------- 4-stage pipelined GRU (128 blocks x 512) -----------------
// role = bx>>5: 0 = G1 (gi1 = xb @ wih1^T + bih1; free-runs), 1 = A (layer-1
// recurrence), 2 = G2 (gi2 = h1 @ wih2^T), 3 = B (layer-2). sub = bx&31 ->
// half = sub>>4, user group b = sub&15. All 4 roles + sibling of one chain
// share an XCD (bx%8 invariant) -> all handoffs are L2-local. ALL flag waits
// are tid==0-gated + barrier-propagated (r13's all-thread spin was the bug).
// h2x is parity double-buffered (closes the lag-1 overwrite race).
__global__ __launch_bounds__(512) void k_pipe(
    const unsigned short* __restrict__ wih1hi, const unsigned short* __restrict__ wih1lo,
    const unsigned short* __restrict__ whh1hi, const unsigned short* __restrict__ whh1lo,
    const unsigned short* __restrict__ wih2hi, const unsigned short* __restrict__ wih2lo,
    const unsigned short* __restrict__ whh2hi, const unsigned short* __restrict__ whh2lo,
    float* __restrict__ gi, unsigned int* __restrict__ pk, unsigned int* __restrict__ h2x,
    const float* __restrict__ bih1, const float* __restrict__ bhh1,
    const float* __restrict__ bih2, const float* __restrict__ bhh2,
    const int* __restrict__ lengths, float* __restrict__ out, int* flags)
{
  __shared__ unsigned short h_hi[16][256], h_lo[16][256];  // 16 KB
  __shared__ unsigned short nlo_s[32768];                  // 64 KB
  int tid = threadIdx.x;
  int l = tid & 63, r = l & 15, g = l >> 4;
  int swv = __builtin_amdgcn_readfirstlane(tid >> 6);
  int bx = blockIdx.x;
  int role = bx >> 5, sub = bx & 31, half = sub >> 4, b = sub & 15;
  int half4 = half * 4;
  int ub = b * 16;
  int jloc = swv * 16 + r, j = half * 128 + jloc;
  int* aflag = flags, *gflag = flags + 32, *bflag = flags + 64, *g1flag = flags + 96;
  int myf = sub, sibf = sub ^ 16;

  const unsigned short* whi_g = (role == 0) ? wih1hi : (role == 1) ? whh1hi
                              : (role == 2) ? wih2hi : whh2hi;
  const unsigned short* wlo_g = (role == 0) ? wih1lo : (role == 1) ? whh1lo
                              : (role == 2) ? wih2lo : whh2lo;
  const float* bb_ = (role == 0) ? bih1 : (role == 1) ? bhh1
                   : (role == 2) ? bih2 : bhh2;

  for (int idx = tid; idx < 4096; idx += 512) {
    ((unsigned short*)h_hi)[idx] = 0;
    ((unsigned short*)h_lo)[idx] = 0;
  }
  // stage this block's n-gate lo rows (its j-half), MFMA-read swizzled
  const unsigned short* wlo_n = wlo_g + 2 * 65536 + half * 128 * 256;
  for (int idx = tid; idx < 32768; idx += 512) {
    int row = idx >> 8, col = idx & 255;
    int slot = (col >> 3) ^ (row & 7);
    nlo_s[row * 256 + slot * 8 + (col & 7)] = wlo_n[idx];
  }
  const unsigned short* w0 = whi_g + (size_t)j * 256 + g * 8;
  const unsigned short* w1 = w0 + 65536;
  const unsigned short* w2 = w0 + 131072;
  float b_r = bb_[j], b_z = bb_[256 + j], b_n = bb_[512 + j];
  int sibbase = (1 - half) * 128;
  int xu = tid >> 5;                           // exchange helper coords
  __syncthreads();

  if (role == 1) {
    // ===== stage A: layer-1 recurrence (j-half) =====
    float hold[4] = {0.f, 0.f, 0.f, 0.f};
    const unsigned int* gq[4];
    unsigned int* hq[4];
    #pragma unroll
    for (int i = 0; i < 4; i++) {
      gq[i] = (const unsigned int*)gi + (size_t)(ub + g * 4 + i) * TT * G3 + j;
      hq[i] = pk + (size_t)(ub + g * 4 + i) * TT * HD + j;
    }
    for (int t = 0; t < TT; t++) {
      v8s cw0[8], cw1[8], cw2[8];
      wload_all(w0, w1, w2, half4, cw0, cw1, cw2);     // 24 weight loads first
      v4f a0 = {0.f,0.f,0.f,0.f}, a1 = {0.f,0.f,0.f,0.f}, a2 = {0.f,0.f,0.f,0.f};
      mfma_run<0,4>(h_hi, h_lo, nlo_s, r, g, jloc, half4, cw0, cw1, cw2, a0, a1, a2);
      if (tid == 0) {                                  // tid0-ONLY waits (r13 bug fix)
        waitflag(&g1flag[b], t + 1);
        waitflag(&g1flag[16 + b], t + 1);
        if (t > 0) waitflag(&aflag[sibf], t);
      }
      __syncthreads();                                 // B1
      if (t > 0) {
        int sj = sibbase + (tid & 31) * 4;
        v4u pkv = *(const v4u*)&pk[((size_t)(ub + xu) * TT + (t - 1)) * HD + sj];
        int pos = (((sj >> 3) ^ (xu & 7)) << 3) + (sj & 7);
        v4us hv, lv;
        #pragma unroll
        for (int i = 0; i < 4; i++) { hv[i] = (unsigned short)(pkv[i] >> 16); lv[i] = (unsigned short)(pkv[i] & 0xffffu); }
        *(v4us*)&h_hi[xu][pos] = hv;
        *(v4us*)&h_lo[xu][pos] = lv;
      }
      unsigned int vr[4], vz[4], vn[4];
      #pragma unroll
      for (int i = 0; i < 4; i++) {                    // gi1(t): L2-hit (G1 same XCD)
        vr[i] = gq[i][0]; vz[i] = gq[i][256]; vn[i] = gq[i][512];
        gq[i] += G3;
      }
      __syncthreads();                                 // B2
      mfma_run<4,8>(h_hi, h_lo, nlo_s, r, g, jloc, half4, cw0, cw1, cw2, a0, a1, a2);
      #pragma unroll
      for (int i = 0; i < 4; i++) {
        float hr = a0[i] + b_r, hz = a1[i] + b_z, hn = a2[i] + b_n;
        float rr = 1.f / (1.f + __expf(-(unpackf(vr[i]) + hr)));
        float zz = 1.f / (1.f + __expf(-(unpackf(vz[i]) + hz)));
        float e  = __expf(2.f * (unpackf(vn[i]) + rr * hn));
        float nn = 1.f - 2.f / (e + 1.f);
        float hnew = (1.f - zz) * nn + zz * hold[i];
        hold[i] = hnew;
        unsigned short h_  = f2b(hnew);
        unsigned short lo_ = f2b(hnew - b2f(h_));
        int u = g * 4 + i;
        int pos = (((j >> 3) ^ (u & 7)) << 3) + (j & 7);
        h_hi[u][pos] = h_;
        h_lo[u][pos] = lo_;
        hq[i][0] = ((unsigned int)h_ << 16) | lo_;     // h1(t) replaces xb(t) slot
        hq[i] += HD;
      }
      __syncthreads();                                 // B3
      if (tid == 0) {
        __threadfence();
        __hip_atomic_store(&aflag[myf], t + 1, __ATOMIC_RELEASE, __HIP_MEMORY_SCOPE_AGENT);
      }
    }
  } else if (role == 3) {
    // ===== stage B: layer-2 recurrence (j-half) =====
    float hold[4] = {0.f, 0.f, 0.f, 0.f};
    const unsigned int* gq[4];
    int lenr[4];
    #pragma unroll
    for (int i = 0; i < 4; i++) {
      gq[i] = (const unsigned int*)gi + (size_t)(ub + g * 4 + i) * TT * G3 + j;
      lenr[i] = lengths[ub + g * 4 + i];
    }
    for (int t = 0; t < TT; t++) {
      v8s cw0[8], cw1[8], cw2[8];
      wload_all(w0, w1, w2, half4, cw0, cw1, cw2);
      v4f a0 = {0.f,0.f,0.f,0.f}, a1 = {0.f,0.f,0.f,0.f}, a2 = {0.f,0.f,0.f,0.f};
      mfma_run<0,4>(h_hi, h_lo, nlo_s, r, g, jloc, half4, cw0, cw1, cw2, a0, a1, a2);
      if (tid == 0) {
        waitflag(&gflag[myf], t + 1);
        if (t > 0) waitflag(&bflag[sibf], t);
      }
      __syncthreads();                                 // B1
      if (t > 0) {
        int sj = sibbase + (tid & 31) * 4;
        v4u pkv = *(const v4u*)&h2x[((t - 1) & 1) * 65536 + (ub + xu) * HD + sj];
        int pos = (((sj >> 3) ^ (xu & 7)) << 3) + (sj & 7);
        v4us hv, lv;
        #pragma unroll
        for (int i = 0; i < 4; i++) { hv[i] = (unsigned short)(pkv[i] >> 16); lv[i] = (unsigned short)(pkv[i] & 0xffffu); }
        *(v4us*)&h_hi[xu][pos] = hv;
        *(v4us*)&h_lo[xu][pos] = lv;
      }
      unsigned int vr[4], vz[4], vn[4];
      #pragma unroll
      for (int i = 0; i < 4; i++) {
        vr[i] = gq[i][0]; vz[i] = gq[i][256]; vn[i] = gq[i][512];
        gq[i] += G3;
      }
      __syncthreads();                                 // B2
      mfma_run<4,8>(h_hi, h_lo, nlo_s, r, g, jloc, half4, cw0, cw1, cw2, a0, a1, a2);
      #pragma unroll
      for (int i = 0; i < 4; i++) {
        float hr = a0[i] + b_r, hz = a1[i] + b_z, hn = a2[i] + b_n;
        float rr = 1.f / (1.f + __expf(-(unpackf(vr[i]) + hr)));
        float zz = 1.f / (1.f + __expf(-(unpackf(vz[i]) + hz)));
        float e  = __expf(2.f * (unpackf(vn[i]) + rr * hn));
        float nn = 1.f - 2.f / (e + 1.f);
        float hnew = (1.f - zz) * nn + zz * hold[i];
        hold[i] = hnew;
        unsigned short h_  = f2b(hnew);
        unsigned short lo_ = f2b(hnew - b2f(h_));
        int u = g * 4 + i;
        int pos = (((j >> 3) ^ (u & 7)) << 3) + (j & 7);
        h_hi[u][pos] = h_;
        h_lo[u][pos] = lo_;
        h2x[(t & 1) * 65536 + (ub + u) * HD + j] = ((unsigned int)h_ << 16) | lo_;
        if (t == lenr[i] - 1)
          out[(size_t)(ub + u) * HD + j] = hnew;
      }
      __syncthreads();                                 // B3
      if (tid == 0) {
        __threadfence();
        __hip_atomic_store(&bflag[myf], t + 1, __ATOMIC_RELEASE, __HIP_MEMORY_SCOPE_AGENT);
      }
    }
  } else {
    // ===== stage G1 (role 0) / G2 (role 2): gi(t) = X(t) @ W^T + bias ======
    // G1: X = xb (pre-staged by k_basket, no wait). G2: X = h1 (wait aflags).
    unsigned int* gi_u = (unsigned int*)gi;
    int* postf = (role == 0) ? &g1flag[myf] : &gflag[myf];
    for (int t = 0; t < TT; t++) {
      v8s cw0[8], cw1[8], cw2[8];
      wload_all(w0, w1, w2, half4, cw0, cw1, cw2);     // hidden under flag wait
      if (role == 2 && tid == 0) { waitflag(&aflag[b], t + 1); waitflag(&aflag[16 + b], t + 1); }
      __syncthreads();                                 // B1
      {
        int c0 = (tid & 31) * 8;
        const unsigned int* src = &pk[((size_t)(ub + xu) * TT + t) * HD + c0];
        #pragma unroll
        for (int hf = 0; hf < 2; hf++) {
          v4u pkv = *(const v4u*)(src + hf * 4);
          int sj = c0 + hf * 4;
          int pos = (((sj >> 3) ^ (xu & 7)) << 3) + (sj & 7);
          v4us hv, lv;
          #pragma unroll
          for (int i = 0; i < 4; i++) { hv[i] = (unsigned short)(pkv[i] >> 16); lv[i] = (unsigned short)(pkv[i] & 0xffffu); }
          *(v4us*)&h_hi[xu][pos] = hv;
          *(v4us*)&h_lo[xu][pos] = lv;
        }
      }
      __syncthreads();                                 // B2
      v4f a0 = {b_r, b_r, b_r, b_r}, a1 = {b_z, b_z, b_z, b_z}, a2 = {b_n, b_n, b_n, b_n};
      mfma_run<0,8>(h_hi, h_lo, nlo_s, r, g, jloc, half4, cw0, cw1, cw2, a0, a1, a2);
      #pragma unroll
      for (int i = 0; i < 4; i++) {
        size_t base = ((size_t)(ub + g * 4 + i) * TT + t) * G3;
        gi_u[base + j]       = packf(a0[i]);
        gi_u[base + 256 + j] = packf(a1[i]);
        gi_u[base + 512 + j] = packf(a2[i]);
      }
      __syncthreads();                                 // B3
      if (tid == 0) {
        __threadfence();
        __hip_atomic_store(postf, t + 1, __ATOMIC_RELEASE, __HIP_MEMORY_SCOPE_AGENT);
      }
    }
  }
}

extern "C" void kernel_launch(void* const* d_in, const int* in_sizes, int n_in,
                              void* d_out, int out_size, void* d_ws, size_t ws_size,
                              hipStream_t stream) {
  const float* prob  = (const float*)d_in[0];
  const int*   seq   = (const int*)d_in[1];
  // d_in[2] = uid (unused by the reference output)
  const float* table = (const float*)d_in[3];
  const float* wih   = (const float*)d_in[4];
  const float* whh   = (const float*)d_in[5];
  const float* bih   = (const float*)d_in[6];
  const float* bhh   = (const float*)d_in[7];
  float* out = (float*)d_out;

  char* ws = (char*)d_ws;
  float* gi          = (float*)ws;                     // 48 MiB packed u32: gi1 -> gi2
  unsigned int* pk   = (unsigned int*)(ws + 50331648); // 16 MiB: packed xb -> packed h1
  char* wsw = ws + 67108864;
  const size_t WSZ = 393216;                           // 768*256*2 B
  unsigned short* wih1hi = (unsigned short*)(wsw + 0 * WSZ);
  unsigned short* wih1lo = (unsigned short*)(wsw + 1 * WSZ);
  unsigned short* wih2hi = (unsigned short*)(wsw + 2 * WSZ);
  unsigned short* wih2lo = (unsigned short*)(wsw + 3 * WSZ);
  unsigned short* whh1hi = (unsigned short*)(wsw + 4 * WSZ);
  unsigned short* whh1lo = (unsigned short*)(wsw + 5 * WSZ);
  unsigned short* whh2hi = (unsigned short*)(wsw + 6 * WSZ);
  unsigned short* whh2lo = (unsigned short*)(wsw + 7 * WSZ);
  int* order   = (int*)(wsw + 8 * WSZ);                // 64 KB
  int* lengths = order + KU * NBASK;
  int* flags   = lengths + KU;
  unsigned int* h2x = (unsigned int*)(wsw + 8 * WSZ + 131072);  // 512 KB (parity x2)

  k_convert<<<dim3(192, 4), 1024, 0, stream>>>(wih, whh,
      wih1hi, wih1lo, wih2hi, wih2lo, whh1hi, whh1lo, whh2hi, whh2lo, flags);
  k_order<<<dim3(KU), 64, 0, stream>>>(prob, seq, order, lengths);
  k_basket<<<dim3(NBASK, KU), 256, 0, stream>>>(prob, seq, table, order, pk);
  // 4-stage pipeline: G1 (gi1) -> A (recur1) -> G2 (gi2) -> B (recur2)
  k_pipe<<<dim3(128), 512, 0, stream>>>(
      wih1hi, wih1lo, whh1hi, whh1lo, wih2hi, wih2lo, whh2hi, whh2lo,
      gi, pk, h2x, bih, bhh, bih + G3, bhh + G3, lengths, out, flags);
}